// Round 8
// baseline (497.670 us; speedup 1.0000x reference)
//
#include <hip/hip_runtime.h>

#define N_NODES 4096
#define C_DIM   128
#define L_LAYERS 4
#define E_EDGES 131072
#define H_HEADS 4
#define D_HEAD  32
#define NC      (N_NODES * C_DIM)
#define NCu     (N_NODES * C_DIM)

typedef short bf16x8 __attribute__((ext_vector_type(8)));
typedef short bf16x4 __attribute__((ext_vector_type(4)));
typedef float f32x4  __attribute__((ext_vector_type(4)));

__device__ __forceinline__ unsigned short f2bf(float f) {
    unsigned int u = __float_as_uint(f);
    u += 0x7fffu + ((u >> 16) & 1u);
    return (unsigned short)(u >> 16);
}

__device__ __forceinline__ float bf_lo(unsigned int u) { return __uint_as_float(u << 16); }
__device__ __forceinline__ float bf_hi(unsigned int u) { return __uint_as_float(u & 0xffff0000u); }

__device__ __forceinline__ bf16x8 pack8(const float* v) {
    bf16x8 o;
#pragma unroll
    for (int i = 0; i < 8; ++i) o[i] = (short)f2bf(v[i]);
    return o;
}

// ---------------------------------------------------------------------------
// CSR build (once per launch)
// ---------------------------------------------------------------------------
__global__ __launch_bounds__(256) void hist_kernel(const int* __restrict__ ei,
                                                   int* __restrict__ deg) {
    int e = blockIdx.x * 256 + threadIdx.x;
    atomicAdd(&deg[ei[E_EDGES + e]], 1);
}

__global__ __launch_bounds__(256) void scan_kernel(const int* __restrict__ deg,
                                                   int* __restrict__ rowstart,
                                                   int* __restrict__ cursor) {
    __shared__ int ts[256];
    const int tid = threadIdx.x;
    int loc[16];
    int s = 0;
#pragma unroll
    for (int i = 0; i < 16; ++i) { loc[i] = s; s += deg[tid * 16 + i]; }
    ts[tid] = s;
    __syncthreads();
    for (int off = 1; off < 256; off <<= 1) {
        int t = (tid >= off) ? ts[tid - off] : 0;
        __syncthreads();
        if (tid >= off) ts[tid] += t;
        __syncthreads();
    }
    int off0 = ts[tid] - s;
#pragma unroll
    for (int i = 0; i < 16; ++i) {
        int v = off0 + loc[i];
        rowstart[tid * 16 + i] = v;
        cursor[tid * 16 + i] = v;
    }
    if (tid == 255) rowstart[4096] = off0 + s;
}

__global__ __launch_bounds__(256) void fill_kernel(const int* __restrict__ ei,
                                                   int* __restrict__ cursor,
                                                   int* __restrict__ csr_src) {
    int e = blockIdx.x * 256 + threadIdx.x;
    int d = ei[E_EDGES + e];
    int s = ei[e];
    int p = atomicAdd(&cursor[d], 1);
    csr_src[p] = s;
}

// ---------------------------------------------------------------------------
// weight pre-convert fp32 -> bf16
// ---------------------------------------------------------------------------
__global__ __launch_bounds__(256) void wcvt(const float* __restrict__ s0, const float* __restrict__ s1,
                                            const float* __restrict__ s2, const float* __restrict__ s3,
                                            const float* __restrict__ s4, const float* __restrict__ s5,
                                            unsigned short* __restrict__ wbf) {
    int i0 = (blockIdx.x * 256 + threadIdx.x) * 8;
    const float* src; int base;
    if      (i0 < 65536)  { src = s0; base = 0; }
    else if (i0 < 131072) { src = s1; base = 65536; }
    else if (i0 < 327680) { src = s2; base = 131072; }
    else if (i0 < 393216) { src = s3; base = 327680; }
    else if (i0 < 524288) { src = s4; base = 393216; }
    else                  { src = s5; base = 524288; }
    const float* p = src + (i0 - base);
    float t[8];
#pragma unroll
    for (int i = 0; i < 8; ++i) t[i] = p[i];
    *(bf16x8*)(wbf + i0) = pack8(t);
}

__global__ __launch_bounds__(256) void x2bf(const float* __restrict__ x,
                                            unsigned short* __restrict__ xb) {
    int i0 = (blockIdx.x * 256 + threadIdx.x) * 8;
    float t[8];
#pragma unroll
    for (int i = 0; i < 8; ++i) t[i] = x[i0 + i];
    *(bf16x8*)(xb + i0) = pack8(t);
}

// ---------------------------------------------------------------------------
// GIN aggregation from bf16 x
// ---------------------------------------------------------------------------
__global__ __launch_bounds__(256) void gather_agg(const unsigned short* __restrict__ xb,
                                                  const int* __restrict__ rowstart,
                                                  const int* __restrict__ csr_src,
                                                  unsigned int* __restrict__ hsum) {
    const int node = blockIdx.x * 4 + (threadIdx.x >> 6);
    const int lane = threadIdx.x & 63;
    const unsigned int* xu = (const unsigned int*)xb;
    const int beg = rowstart[node], end = rowstart[node + 1];
    unsigned int su = xu[(size_t)node * 64 + lane];
    float ax = bf_lo(su), ay = bf_hi(su);
    float bx = 0.f, by = 0.f;
    int e = beg;
    for (; e + 4 <= end; e += 4) {
        int s0 = csr_src[e], s1 = csr_src[e + 1], s2 = csr_src[e + 2], s3 = csr_src[e + 3];
        unsigned int u0 = xu[(size_t)s0 * 64 + lane];
        unsigned int u1 = xu[(size_t)s1 * 64 + lane];
        unsigned int u2 = xu[(size_t)s2 * 64 + lane];
        unsigned int u3 = xu[(size_t)s3 * 64 + lane];
        ax += bf_lo(u0) + bf_lo(u1); ay += bf_hi(u0) + bf_hi(u1);
        bx += bf_lo(u2) + bf_lo(u3); by += bf_hi(u2) + bf_hi(u3);
    }
    for (; e < end; ++e) {
        unsigned int u0 = xu[(size_t)csr_src[e] * 64 + lane];
        ax += bf_lo(u0); ay += bf_hi(u0);
    }
    float ox = ax + bx, oy = ay + by;
    hsum[(size_t)node * 64 + lane] = (unsigned int)f2bf(ox) | ((unsigned int)f2bf(oy) << 16);
}

// ---------------------------------------------------------------------------
// bf16 MFMA GEMM, LDS-free, 16x16 tile per wave. grid (J/64, N/16).
// ---------------------------------------------------------------------------
template <int K>
__global__ __launch_bounds__(256, 8) void gemm_bf(const unsigned short* __restrict__ Abf,
                                                  const unsigned short* __restrict__ Wbf,
                                                  const float* __restrict__ bias,
                                                  const float* __restrict__ resid,
                                                  float* __restrict__ outf,
                                                  unsigned short* __restrict__ outb,
                                                  const int J, const int relu) {
    const int tid = threadIdx.x;
    const int wv = tid >> 6;
    const int lane = tid & 63, lg = lane >> 4, ll = lane & 15;
    const int rowbase = blockIdx.y * 16;
    const int colbase = blockIdx.x * 64 + wv * 16;

    const unsigned short* Ap = Abf + (size_t)(rowbase + ll) * K + lg * 8;
    const unsigned short* Wp = Wbf + (size_t)(colbase + ll) * K + lg * 8;

    f32x4 acc = {0.f, 0.f, 0.f, 0.f};
#pragma unroll
    for (int k = 0; k < K; k += 32) {
        bf16x8 a = *(const bf16x8*)(Ap + k);
        bf16x8 b = *(const bf16x8*)(Wp + k);
        acc = __builtin_amdgcn_mfma_f32_16x16x32_bf16(a, b, acc, 0, 0, 0);
    }

    const int col = colbase + ll;
    const float bi = bias[col];
#pragma unroll
    for (int r = 0; r < 4; ++r) {
        const int row = rowbase + lg * 4 + r;
        float v = acc[r] + bi;
        if (resid) v += resid[(size_t)row * J + col];
        if (relu) v = fmaxf(v, 0.f);
        if (outf) outf[(size_t)row * J + col] = v;
        if (outb) outb[(size_t)row * J + col] = f2bf(v);
    }
}

// ---------------------------------------------------------------------------
// QKV GEMM with layout epilogue: Qb [H][N][32] (pre-scaled), Kb [H][N][32],
// VT [H][32][N].  grid (6, 256).
// ---------------------------------------------------------------------------
__global__ __launch_bounds__(256, 8) void gemm_qkv_bf(const unsigned short* __restrict__ Abf,
                                                      const unsigned short* __restrict__ Wbf,
                                                      const float* __restrict__ bias,
                                                      unsigned short* __restrict__ Qb,
                                                      unsigned short* __restrict__ Kb,
                                                      unsigned short* __restrict__ VT) {
    const int tid = threadIdx.x;
    const int wv = tid >> 6;
    const int lane = tid & 63, lg = lane >> 4, ll = lane & 15;
    const int rowbase = blockIdx.y * 16;
    const int colbase = blockIdx.x * 64 + wv * 16;

    const unsigned short* Ap = Abf + (size_t)(rowbase + ll) * 128 + lg * 8;
    const unsigned short* Wp = Wbf + (size_t)(colbase + ll) * 128 + lg * 8;

    f32x4 acc = {0.f, 0.f, 0.f, 0.f};
#pragma unroll
    for (int k = 0; k < 128; k += 32) {
        bf16x8 a = *(const bf16x8*)(Ap + k);
        bf16x8 b = *(const bf16x8*)(Wp + k);
        acc = __builtin_amdgcn_mfma_f32_16x16x32_bf16(a, b, acc, 0, 0, 0);
    }

    const float qsc = 0.25506973f;  // (1/sqrt(32)) * log2(e)
    const int col = colbase + ll;
    const float bi = bias[col];
#pragma unroll
    for (int r = 0; r < 4; ++r) {
        const int row = rowbase + lg * 4 + r;
        float v = acc[r] + bi;
        if (col < 128) {
            int hh = col >> 5, d = col & 31;
            Qb[((size_t)hh * N_NODES + row) * D_HEAD + d] = f2bf(v * qsc);
        } else if (col < 256) {
            int c2 = col - 128, hh = c2 >> 5, d = c2 & 31;
            Kb[((size_t)hh * N_NODES + row) * D_HEAD + d] = f2bf(v);
        } else {
            int c2 = col - 256, hh = c2 >> 5, d = c2 & 31;
            VT[((size_t)hh * D_HEAD + d) * N_NODES + row] = f2bf(v);
        }
    }
}

// ---------------------------------------------------------------------------
// Flash attention v5 — swapped-operand QK^T, P stays in-lane, ZERO flash-loop
// LDS. grid (N/32, H), 512 thr = 8 waves, 8-way key split.
//   QK: mfma(K, Q) -> D[col=q=ll][row=key=kc*16+lg*4+r]: lane owns q=ll for
//   32 keys. exp2 + bf16-pack immediately (no max shift; scores bounded).
//   PV: k-slot permutation key(kappa)=32j+(i>>2)*16+lg*4+(i&3) matches the
//   lane's held keys; V read with the SAME permutation (two 8B runs/frag).
//   Sum over k-slots is permutation-invariant => exact same math as v4.
// ---------------------------------------------------------------------------
__global__ __launch_bounds__(512, 4) void attn_kernel(const unsigned short* __restrict__ Qb,
                                                      const unsigned short* __restrict__ Kb,
                                                      const unsigned short* __restrict__ VT,
                                                      unsigned short* __restrict__ ob) {
    __shared__ float Ouns[8][32][33];   // 33792 B
    __shared__ float Llp[8][32];        //  1024 B

    const int h   = blockIdx.y;
    const int q0  = blockIdx.x * 32;
    const int tid = threadIdx.x;
    const int wv  = tid >> 6;
    const int lane = tid & 63;
    const int lg  = lane >> 4;
    const int ll  = lane & 15;

    const unsigned short* Qh = Qb + ((size_t)h * N_NODES + q0) * D_HEAD;
    const unsigned short* Kh = Kb + (size_t)h * N_NODES * D_HEAD;
    const unsigned short* Vh = VT + (size_t)h * D_HEAD * N_NODES;

    // Q as B-operand: lane holds Q[q=ll][d=lg*8+i] (same bytes as before)
    bf16x8 qf0 = *(const bf16x8*)(Qh + ll * D_HEAD + lg * 8);
    bf16x8 qf1 = *(const bf16x8*)(Qh + (16 + ll) * D_HEAD + lg * 8);

    f32x4 o00 = {0.f,0.f,0.f,0.f}, o01 = {0.f,0.f,0.f,0.f};
    f32x4 o10 = {0.f,0.f,0.f,0.f}, o11 = {0.f,0.f,0.f,0.f};
    float l0 = 0.f, l1 = 0.f;   // lane-local softmax denominators (q=ll, 16+ll)

    const int k0 = wv * (N_NODES / 8);
    const unsigned short* Vrow_lo = Vh + (size_t)ll * N_NODES;
    const unsigned short* Vrow_hi = Vh + (size_t)(16 + ll) * N_NODES;

    for (int t = 0; t < (N_NODES / 8) / 128; ++t) {
        const int kt = k0 + t * 128;

        // QK^T (A=K, B=Q) + exp2 + in-lane bf16 pack
        bf16x8 pa0[4], pa1[4];
#pragma unroll
        for (int kc = 0; kc < 8; ++kc) {
            bf16x8 kf = *(const bf16x8*)(Kh + (size_t)(kt + kc * 16 + ll) * D_HEAD + lg * 8);
            f32x4 z = {0.f, 0.f, 0.f, 0.f};
            f32x4 d0 = __builtin_amdgcn_mfma_f32_16x16x32_bf16(kf, qf0, z, 0, 0, 0);
            f32x4 d1 = __builtin_amdgcn_mfma_f32_16x16x32_bf16(kf, qf1, z, 0, 0, 0);
#pragma unroll
            for (int r = 0; r < 4; ++r) {
                float p0 = exp2f(d0[r]); l0 += p0;
                float p1 = exp2f(d1[r]); l1 += p1;
                pa0[kc >> 1][(kc & 1) * 4 + r] = (short)f2bf(p0);
                pa1[kc >> 1][(kc & 1) * 4 + r] = (short)f2bf(p1);
            }
        }

        // PV: V read with the matching per-lane key permutation
#pragma unroll
        for (int j = 0; j < 4; ++j) {
            const int kb = kt + 32 * j + lg * 4;
            bf16x4 alo0 = *(const bf16x4*)(Vrow_lo + kb);
            bf16x4 alo1 = *(const bf16x4*)(Vrow_lo + kb + 16);
            bf16x4 ahi0 = *(const bf16x4*)(Vrow_hi + kb);
            bf16x4 ahi1 = *(const bf16x4*)(Vrow_hi + kb + 16);
            bf16x8 vlo = __builtin_shufflevector(alo0, alo1, 0, 1, 2, 3, 4, 5, 6, 7);
            bf16x8 vhi = __builtin_shufflevector(ahi0, ahi1, 0, 1, 2, 3, 4, 5, 6, 7);
            o00 = __builtin_amdgcn_mfma_f32_16x16x32_bf16(pa0[j], vlo, o00, 0, 0, 0);
            o01 = __builtin_amdgcn_mfma_f32_16x16x32_bf16(pa0[j], vhi, o01, 0, 0, 0);
            o10 = __builtin_amdgcn_mfma_f32_16x16x32_bf16(pa1[j], vlo, o10, 0, 0, 0);
            o11 = __builtin_amdgcn_mfma_f32_16x16x32_bf16(pa1[j], vhi, o11, 0, 0, 0);
        }
    }

    // finish lane-local denominators: sum the 4 lg-groups holding same q
    l0 += __shfl_xor(l0, 16, 64); l0 += __shfl_xor(l0, 32, 64);
    l1 += __shfl_xor(l1, 16, 64); l1 += __shfl_xor(l1, 32, 64);

    // publish per-wave partials. O layout: lane (lg,ll): O[q=lg*4+r][d=ll|16+ll]
#pragma unroll
    for (int r = 0; r < 4; ++r) {
        Ouns[wv][lg * 4 + r][ll]           = o00[r];
        Ouns[wv][lg * 4 + r][16 + ll]      = o01[r];
        Ouns[wv][16 + lg * 4 + r][ll]      = o10[r];
        Ouns[wv][16 + lg * 4 + r][16 + ll] = o11[r];
    }
    if (lg == 0) {
        Llp[wv][ll]      = l0;
        Llp[wv][16 + ll] = l1;
    }
    __syncthreads();

    // merge 8 key-split partials; 512 thr = 32 rows x 16 cols (2 cols each)
    {
        const int row = tid >> 4, col = tid & 15;
        float L = 0.f, oa = 0.f, obv = 0.f;
#pragma unroll
        for (int w = 0; w < 8; ++w) {
            L   += Llp[w][row];
            oa  += Ouns[w][row][col];
            obv += Ouns[w][row][16 + col];
        }
        float inv = 1.f / L;
        ob[(size_t)(q0 + row) * C_DIM + h * D_HEAD + col]      = f2bf(oa * inv);
        ob[(size_t)(q0 + row) * C_DIM + h * D_HEAD + 16 + col] = f2bf(obv * inv);
    }
}

// ---------------------------------------------------------------------------
// fused double BatchNorm stats
// ---------------------------------------------------------------------------
__global__ __launch_bounds__(256) void bn_stats2(const float* __restrict__ in1,
                                                 const float* __restrict__ g1v,
                                                 const float* __restrict__ b1v,
                                                 float* __restrict__ ss1,
                                                 const float* __restrict__ in2,
                                                 const float* __restrict__ g2v,
                                                 const float* __restrict__ b2v,
                                                 float* __restrict__ ss2) {
    const int which = blockIdx.x >> 5;
    const int c4 = blockIdx.x & 31;
    const float* in = which ? in2 : in1;
    const float* g  = which ? g2v : g1v;
    const float* b  = which ? b2v : b1v;
    float* ss       = which ? ss2 : ss1;
    const int tid = threadIdx.x;
    float s[4] = {0.f,0.f,0.f,0.f}, s2[4] = {0.f,0.f,0.f,0.f};
    for (int r = tid; r < N_NODES; r += 256) {
        float4 v = *(const float4*)(in + (size_t)r * C_DIM + c4 * 4);
        s[0] += v.x; s2[0] += v.x * v.x;
        s[1] += v.y; s2[1] += v.y * v.y;
        s[2] += v.z; s2[2] += v.z * v.z;
        s[3] += v.w; s2[3] += v.w * v.w;
    }
#pragma unroll
    for (int off = 1; off < 64; off <<= 1) {
#pragma unroll
        for (int c = 0; c < 4; ++c) {
            s[c]  += __shfl_xor(s[c],  off, 64);
            s2[c] += __shfl_xor(s2[c], off, 64);
        }
    }
    __shared__ float red[4][8];
    int w = tid >> 6;
    if ((tid & 63) == 0) {
#pragma unroll
        for (int c = 0; c < 4; ++c) { red[w][c] = s[c]; red[w][4 + c] = s2[c]; }
    }
    __syncthreads();
    if (tid == 0) {
#pragma unroll
        for (int c = 0; c < 4; ++c) {
            float fs = red[0][c] + red[1][c] + red[2][c] + red[3][c];
            float fs2 = red[0][4 + c] + red[1][4 + c] + red[2][4 + c] + red[3][4 + c];
            int ch = c4 * 4 + c;
            float mean = fs / N_NODES;
            float var = fs2 / N_NODES - mean * mean;
            float rstd = rsqrtf(var + 1e-5f);
            float scale = g[ch] * rstd;
            ss[ch] = scale;
            ss[C_DIM + ch] = b[ch] - mean * scale;
        }
    }
}

__global__ __launch_bounds__(256) void bn_stats(const float* __restrict__ in,
                                                const float* __restrict__ g,
                                                const float* __restrict__ b,
                                                float* __restrict__ ss) {
    const int c4 = blockIdx.x;
    const int tid = threadIdx.x;
    float s[4] = {0.f,0.f,0.f,0.f}, s2[4] = {0.f,0.f,0.f,0.f};
    for (int r = tid; r < N_NODES; r += 256) {
        float4 v = *(const float4*)(in + (size_t)r * C_DIM + c4 * 4);
        s[0] += v.x; s2[0] += v.x * v.x;
        s[1] += v.y; s2[1] += v.y * v.y;
        s[2] += v.z; s2[2] += v.z * v.z;
        s[3] += v.w; s2[3] += v.w * v.w;
    }
#pragma unroll
    for (int off = 1; off < 64; off <<= 1) {
#pragma unroll
        for (int c = 0; c < 4; ++c) {
            s[c]  += __shfl_xor(s[c],  off, 64);
            s2[c] += __shfl_xor(s2[c], off, 64);
        }
    }
    __shared__ float red[4][8];
    int w = tid >> 6;
    if ((tid & 63) == 0) {
#pragma unroll
        for (int c = 0; c < 4; ++c) { red[w][c] = s[c]; red[w][4 + c] = s2[c]; }
    }
    __syncthreads();
    if (tid == 0) {
#pragma unroll
        for (int c = 0; c < 4; ++c) {
            float fs = red[0][c] + red[1][c] + red[2][c] + red[3][c];
            float fs2 = red[0][4 + c] + red[1][4 + c] + red[2][4 + c] + red[3][4 + c];
            int ch = c4 * 4 + c;
            float mean = fs / N_NODES;
            float var = fs2 / N_NODES - mean * mean;
            float rstd = rsqrtf(var + 1e-5f);
            float scale = g[ch] * rstd;
            ss[ch] = scale;
            ss[C_DIM + ch] = b[ch] - mean * scale;
        }
    }
}

__global__ __launch_bounds__(256) void combine2(const float* __restrict__ p1,
                                                const float* __restrict__ p2,
                                                const float* __restrict__ ss1,
                                                const float* __restrict__ ss2,
                                                float* __restrict__ out,
                                                unsigned short* __restrict__ outb) {
    int idx = blockIdx.x * 256 + threadIdx.x;
    int c4 = (idx & 31) * 4;
    float4 v1 = ((const float4*)p1)[idx];
    float4 v2 = ((const float4*)p2)[idx];
    float4 sc1 = *(const float4*)(ss1 + c4), sh1 = *(const float4*)(ss1 + C_DIM + c4);
    float4 sc2 = *(const float4*)(ss2 + c4), sh2 = *(const float4*)(ss2 + C_DIM + c4);
    float4 o;
    o.x = v1.x * sc1.x + sh1.x + v2.x * sc2.x + sh2.x;
    o.y = v1.y * sc1.y + sh1.y + v2.y * sc2.y + sh2.y;
    o.z = v1.z * sc1.z + sh1.z + v2.z * sc2.z + sh2.z;
    o.w = v1.w * sc1.w + sh1.w + v2.w * sc2.w + sh2.w;
    ((float4*)out)[idx] = o;
    ushort4 ub;
    ub.x = f2bf(o.x); ub.y = f2bf(o.y); ub.z = f2bf(o.z); ub.w = f2bf(o.w);
    *(ushort4*)(outb + (size_t)idx * 4) = ub;
}

__global__ __launch_bounds__(256) void bn_apply(const float* __restrict__ p,
                                                const float* __restrict__ ss,
                                                float* __restrict__ out,
                                                unsigned short* __restrict__ outb) {
    int idx = blockIdx.x * 256 + threadIdx.x;
    int c4 = (idx & 31) * 4;
    float4 v = ((const float4*)p)[idx];
    float4 sc = *(const float4*)(ss + c4), sh = *(const float4*)(ss + C_DIM + c4);
    float4 o;
    o.x = v.x * sc.x + sh.x;
    o.y = v.y * sc.y + sh.y;
    o.z = v.z * sc.z + sh.z;
    o.w = v.w * sc.w + sh.w;
    ((float4*)out)[idx] = o;
    ushort4 ub;
    ub.x = f2bf(o.x); ub.y = f2bf(o.y); ub.z = f2bf(o.z); ub.w = f2bf(o.w);
    *(ushort4*)(outb + (size_t)idx * 4) = ub;
}

// ---------------------------------------------------------------------------
// Fused head MLP
// ---------------------------------------------------------------------------
__global__ __launch_bounds__(256) void head_fused(const float* __restrict__ x,
                                                  const float* __restrict__ w1,
                                                  const float* __restrict__ b1,
                                                  const float* __restrict__ w2,
                                                  const float* __restrict__ b2,
                                                  const float* __restrict__ w3,
                                                  const float* __restrict__ b3,
                                                  float* __restrict__ out) {
    __shared__ __align__(16) float xs[8][128];
    __shared__ __align__(16) float hs[8][64];
    const int tid = threadIdx.x;
    const int n = tid >> 5;
    const int g = tid & 31;
    const int node0 = blockIdx.x * 8;

    {
        int r = tid >> 5, q = tid & 31;
        *(float4*)(&xs[r][q * 4]) = *(const float4*)(x + (size_t)(node0 + r) * 128 + q * 4);
    }
    __syncthreads();

    {
        float acc0 = b1[g], acc1 = b1[g + 32];
        const float* wa = w1 + (size_t)g * 128;
        const float* wb = w1 + (size_t)(g + 32) * 128;
#pragma unroll 8
        for (int k = 0; k < 128; k += 4) {
            float4 xv = *(const float4*)(&xs[n][k]);
            float4 va = *(const float4*)(wa + k);
            float4 vb = *(const float4*)(wb + k);
            acc0 += xv.x * va.x + xv.y * va.y + xv.z * va.z + xv.w * va.w;
            acc1 += xv.x * vb.x + xv.y * vb.y + xv.z * vb.z + xv.w * vb.w;
        }
        hs[n][g]      = fmaxf(acc0, 0.f);
        hs[n][g + 32] = fmaxf(acc1, 0.f);
    }
    __syncthreads();

    {
        float acc = b2[g];
        const float* wr = w2 + (size_t)g * 64;
#pragma unroll 8
        for (int k = 0; k < 64; k += 4) {
            float4 hv = *(const float4*)(&hs[n][k]);
            float4 wv = *(const float4*)(wr + k);
            acc += hv.x * wv.x + hv.y * wv.y + hv.z * wv.z + hv.w * wv.w;
        }
        float t = fmaxf(acc, 0.f) * w3[g];
#pragma unroll
        for (int off = 1; off < 32; off <<= 1) t += __shfl_xor(t, off, 64);
        if (g == 0) out[node0 + n] = t + b3[0];
    }
}

// ---------------------------------------------------------------------------
extern "C" void kernel_launch(void* const* d_in, const int* in_sizes, int n_in,
                              void* d_out, int out_size, void* d_ws, size_t ws_size,
                              hipStream_t stream) {
    (void)in_sizes; (void)n_in; (void)out_size; (void)ws_size;
    const float* x_in   = (const float*)d_in[0];
    const int*   ei     = (const int*)d_in[1];
    const float* gin_w1 = (const float*)d_in[2];
    const float* gin_b1 = (const float*)d_in[3];
    const float* gin_w2 = (const float*)d_in[4];
    const float* gin_b2 = (const float*)d_in[5];
    const float* ain_w  = (const float*)d_in[6];
    const float* ain_b  = (const float*)d_in[7];
    const float* aout_w = (const float*)d_in[8];
    const float* aout_b = (const float*)d_in[9];
    const float* n1_g   = (const float*)d_in[10];
    const float* n1_b   = (const float*)d_in[11];
    const float* n2_g   = (const float*)d_in[12];
    const float* n2_b   = (const float*)d_in[13];
    const float* n3_g   = (const float*)d_in[14];
    const float* n3_b   = (const float*)d_in[15];
    const float* mlp_w1 = (const float*)d_in[16];
    const float* mlp_b1 = (const float*)d_in[17];
    const float* mlp_w2 = (const float*)d_in[18];
    const float* mlp_b2 = (const float*)d_in[19];
    const float* h_w1   = (const float*)d_in[20];
    const float* h_b1   = (const float*)d_in[21];
    const float* h_w2   = (const float*)d_in[22];
    const float* h_b2   = (const float*)d_in[23];
    const float* h_w3   = (const float*)d_in[24];
    const float* h_b3   = (const float*)d_in[25];

    float* f = (float*)d_ws;
    float* g1   = f;                 // c0; m3 aliases (g1 dead after combine2)
    float* m3   = f;
    float* a2   = f + 1 * (size_t)NC;
    float* hbuf = f + 2 * (size_t)NC;
    float* xA   = f + 3 * (size_t)NC;
    float* xB   = f + 4 * (size_t)NC;
    unsigned short* R1  = (unsigned short*)(f + 5 * (size_t)NC);  // 3 NCu
    unsigned short* hsum_bf = R1;
    unsigned short* t1_bf   = R1 + (size_t)NCu;
    unsigned short* Qb      = R1;
    unsigned short* Kb      = R1 + (size_t)NCu;
    unsigned short* VT      = R1 + 2 * (size_t)NCu;
    unsigned short* t2_bf   = R1;
    unsigned short* R2      = R1 + 3 * (size_t)NCu;
    unsigned short* ao_bf   = R2;
    unsigned short* hbuf_bf = R2;
    unsigned short* xbf     = R2 + (size_t)NCu;
    unsigned short* wbf     = xbf + (size_t)NCu;
    float* ss    = (float*)(wbf + 655360);
    int* ibase    = (int*)(ss + 768);
    int* deg      = ibase;
    int* rowstart = ibase + 4096;
    int* cursor   = ibase + 4096 + 4098;
    int* csr_src  = ibase + 4096 + 4098 + 4096;

    const int OG1 = 0, OG2 = 65536, OAI = 131072, OAO = 327680, OM1 = 393216, OM2 = 524288;

    hipMemsetAsync(deg, 0, 4096 * sizeof(int), stream);
    hist_kernel<<<E_EDGES / 256, 256, 0, stream>>>(ei, deg);
    scan_kernel<<<1, 256, 0, stream>>>(deg, rowstart, cursor);
    fill_kernel<<<E_EDGES / 256, 256, 0, stream>>>(ei, cursor, csr_src);
    wcvt<<<320, 256, 0, stream>>>(gin_w1, gin_w2, ain_w, aout_w, mlp_w1, mlp_w2, wbf);
    x2bf<<<NC / 2048, 256, 0, stream>>>(x_in, xbf);

    for (int i = 0; i < L_LAYERS; ++i) {
        const float* xin = (i == 0) ? x_in : ((i & 1) ? xA : xB);
        float* xout = (i & 1) ? xB : xA;
        const float* gb1 = gin_b1 + (size_t)i * C_DIM;
        const float* gb2 = gin_b2 + (size_t)i * C_DIM;
        const float* aib = ain_b + (size_t)i * 3 * C_DIM;
        const float* aob = aout_b + (size_t)i * C_DIM;
        const float* mb1 = mlp_b1 + (size_t)i * 2 * C_DIM;
        const float* mb2 = mlp_b2 + (size_t)i * C_DIM;

        // GIN branch (gathers bf16 x)
        gather_agg<<<N_NODES / 4, 256, 0, stream>>>(xbf, rowstart, csr_src, (unsigned int*)hsum_bf);
        gemm_bf<128><<<dim3(2, 256), 256, 0, stream>>>(hsum_bf, wbf + OG1 + (size_t)i * 16384,
                                                       gb1, nullptr, nullptr, t1_bf, 128, 1);
        gemm_bf<128><<<dim3(2, 256), 256, 0, stream>>>(t1_bf, wbf + OG2 + (size_t)i * 16384,
                                                       gb2, xin, g1, nullptr, 128, 0);
        // attention branch
        gemm_qkv_bf<<<dim3(6, 256), 256, 0, stream>>>(xbf, wbf + OAI + (size_t)i * 49152,
                                                      aib, Qb, Kb, VT);
        attn_kernel<<<dim3(N_NODES / 32, H_HEADS), 512, 0, stream>>>(Qb, Kb, VT, ao_bf);
        gemm_bf<128><<<dim3(2, 256), 256, 0, stream>>>(ao_bf, wbf + OAO + (size_t)i * 16384,
                                                       aob, xin, a2, nullptr, 128, 0);
        // norms + combine
        bn_stats2<<<64, 256, 0, stream>>>(g1, n1_g + (size_t)i * C_DIM, n1_b + (size_t)i * C_DIM, ss,
                                          a2, n2_g + (size_t)i * C_DIM, n2_b + (size_t)i * C_DIM, ss + 256);
        combine2<<<512, 256, 0, stream>>>(g1, a2, ss, ss + 256, hbuf, hbuf_bf);
        // MLP
        gemm_bf<128><<<dim3(4, 256), 256, 0, stream>>>(hbuf_bf, wbf + OM1 + (size_t)i * 32768,
                                                       mb1, nullptr, nullptr, t2_bf, 256, 1);
        gemm_bf<256><<<dim3(2, 256), 256, 0, stream>>>(t2_bf, wbf + OM2 + (size_t)i * 32768,
                                                       mb2, hbuf, m3, nullptr, 128, 0);
        bn_stats<<<32, 256, 0, stream>>>(m3, n3_g + (size_t)i * C_DIM, n3_b + (size_t)i * C_DIM, ss + 512);
        bn_apply<<<512, 256, 0, stream>>>(m3, ss + 512, xout, xbf);
    }

    const float* xf = xB;  // after layer 3
    head_fused<<<N_NODES / 8, 256, 0, stream>>>(xf, h_w1, h_b1, h_w2, h_b2, h_w3, h_b3,
                                                (float*)d_out);
}